// Round 3
// baseline (314.095 us; speedup 1.0000x reference)
//
#include <hip/hip_runtime.h>

// GroupBatchNorm: B=512, C=65536, G=4096, fp32 in/out.
// Memory-bound: ~384 MiB min traffic -> ~61 us floor @ 6.3 TB/s.
//
// Pipeline:
//   zero_k    : zero the atomic accumulators (device-global scratch, no d_ws)
//   colsum_k  : per-channel sum/sumsq over batch chunks (float4, atomic combine)
//   gscatter_k: channel sums -> group sums (atomic, ~16 ch/group)
//   finalize_k: group mean/var -> fused scale/shift (gamma,beta folded in)
//   cgather_k : group scale/shift -> per-channel tables (kills indirection)
//   norm_k    : streaming out = x*scale + shift, float4
//
// Scratch lives in a __device__ global (1.13 MB) instead of d_ws: removes any
// dependence on ws_size (an undersized d_ws -> OOB atomics -> device fault was
// the one self-inflicted explanation for the container dying). zero_k re-inits
// every call, so no cross-call state survives.

constexpr int B = 512;
constexpr int C = 65536;
constexpr int G = 4096;
constexpr int SPLIT = 16;         // batch chunks for stage-1 parallelism
constexpr int ROWS = B / SPLIT;   // 32 rows per chunk
#define EPS 1e-5f

// Scratch layout (floats):
//   [0,C)          csum      per-channel sum
//   [C,2C)         csum2     per-channel sumsq
//   [2C,2C+G)      gsum
//   [2C+G,2C+2G)   gsum2
//   [2C+2G,2C+3G)  gcnt
//   [2C+3G,2C+4G)  gscale
//   [2C+4G,2C+5G)  gshift
//   [2C+5G,3C+5G)  cscale    per-channel fused scale
//   [3C+5G,4C+5G)  cshift    per-channel fused shift
constexpr int SCRATCH_N = 4 * C + 5 * G;
__device__ float g_scr[SCRATCH_N];

#define CSUM   (g_scr)
#define CSUM2  (g_scr + C)
#define GSUM   (g_scr + 2 * C)
#define GSUM2  (g_scr + 2 * C + G)
#define GCNT   (g_scr + 2 * C + 2 * G)
#define GSCALE (g_scr + 2 * C + 3 * G)
#define GSHIFT (g_scr + 2 * C + 4 * G)
#define CSCALE (g_scr + 2 * C + 5 * G)
#define CSHIFT (g_scr + 3 * C + 5 * G)

// Zero the atomic-accumulator region [0, 2C+3G).
__global__ __launch_bounds__(256) void zero_k() {
    int i = blockIdx.x * 256 + threadIdx.x;
    if (i < 2 * C + 3 * G) g_scr[i] = 0.0f;
}

// Stage 1: each thread owns 4 consecutive channels (one float4 per row).
// grid = (C/1024) * SPLIT blocks of 256 threads.
__global__ __launch_bounds__(256) void colsum_k(const float* __restrict__ x) {
    const int nblk_c = C / 1024;                               // 64
    const int c4 = (blockIdx.x % nblk_c) * 256 + threadIdx.x;  // channel-quad idx
    const int chunk = blockIdx.x / nblk_c;
    const float4* __restrict__ xp =
        (const float4*)(x + (size_t)chunk * ROWS * C) + c4;
    float4 s = {0.f, 0.f, 0.f, 0.f};
    float4 s2 = {0.f, 0.f, 0.f, 0.f};
#pragma unroll 4
    for (int r = 0; r < ROWS; ++r) {
        float4 v = xp[(size_t)r * (C / 4)];
        s.x += v.x; s.y += v.y; s.z += v.z; s.w += v.w;
        s2.x = fmaf(v.x, v.x, s2.x);
        s2.y = fmaf(v.y, v.y, s2.y);
        s2.z = fmaf(v.z, v.z, s2.z);
        s2.w = fmaf(v.w, v.w, s2.w);
    }
    const int c = c4 * 4;
    atomicAdd(&CSUM[c + 0], s.x);
    atomicAdd(&CSUM[c + 1], s.y);
    atomicAdd(&CSUM[c + 2], s.z);
    atomicAdd(&CSUM[c + 3], s.w);
    atomicAdd(&CSUM2[c + 0], s2.x);
    atomicAdd(&CSUM2[c + 1], s2.y);
    atomicAdd(&CSUM2[c + 2], s2.z);
    atomicAdd(&CSUM2[c + 3], s2.w);
}

// Stage 2: scatter per-channel sums into per-group accumulators.
__global__ __launch_bounds__(256) void gscatter_k(const int* __restrict__ cg) {
    const int c = blockIdx.x * 256 + threadIdx.x;
    const int g = cg[c];
    atomicAdd(&GSUM[g], CSUM[c]);
    atomicAdd(&GSUM2[g], CSUM2[c]);
    atomicAdd(&GCNT[g], 1.0f);
}

// Stage 3: per-group mean/var -> fused affine scale/shift.
__global__ __launch_bounds__(256) void finalize_k(const float* __restrict__ gamma,
                                                  const float* __restrict__ beta) {
    const int g = blockIdx.x * 256 + threadIdx.x;
    if (g < G) {
        float cnt = fmaxf(GCNT[g] * (float)B, 1.0f);
        float mean = GSUM[g] / cnt;
        float var = GSUM2[g] / cnt - mean * mean;
        float inv = 1.0f / sqrtf(var + EPS);
        float sc = gamma[g] * inv;
        GSCALE[g] = sc;
        GSHIFT[g] = fmaf(-mean, sc, beta[g]);
    }
}

// Stage 4: expand group scale/shift to per-channel tables (512 KB, L2-resident).
__global__ __launch_bounds__(256) void cgather_k(const int* __restrict__ cg) {
    const int c = blockIdx.x * 256 + threadIdx.x;
    const int g = cg[c];
    CSCALE[c] = GSCALE[g];
    CSHIFT[c] = GSHIFT[g];
}

// Stage 5: streaming normalize, float4 everywhere.
__global__ __launch_bounds__(256) void norm_k(const float* __restrict__ x,
                                              float* __restrict__ out) {
    const float4* __restrict__ x4 = (const float4*)x;
    const float4* __restrict__ sc4 = (const float4*)CSCALE;
    const float4* __restrict__ sh4 = (const float4*)CSHIFT;
    float4* __restrict__ o4 = (float4*)out;
    const size_t n4 = (size_t)B * C / 4;
    const size_t stride = (size_t)gridDim.x * blockDim.x;
    for (size_t i = (size_t)blockIdx.x * blockDim.x + threadIdx.x; i < n4; i += stride) {
        const int c4 = (int)(i & (C / 4 - 1));  // channel-quad index (C/4 pow2)
        float4 xv = x4[i];
        float4 s = sc4[c4];
        float4 t = sh4[c4];
        float4 o;
        o.x = fmaf(xv.x, s.x, t.x);
        o.y = fmaf(xv.y, s.y, t.y);
        o.z = fmaf(xv.z, s.z, t.z);
        o.w = fmaf(xv.w, s.w, t.w);
        o4[i] = o;
    }
}

extern "C" void kernel_launch(void* const* d_in, const int* in_sizes, int n_in,
                              void* d_out, int out_size, void* d_ws, size_t ws_size,
                              hipStream_t stream) {
    const float* x = (const float*)d_in[0];
    const int* cg = (const int*)d_in[1];
    const float* gamma = (const float*)d_in[2];
    const float* beta = (const float*)d_in[3];
    float* out = (float*)d_out;
    (void)d_ws; (void)ws_size; (void)in_sizes; (void)n_in; (void)out_size;

    constexpr int nzero = 2 * C + 3 * G;
    zero_k<<<(nzero + 255) / 256, 256, 0, stream>>>();
    colsum_k<<<(C / 1024) * SPLIT, 256, 0, stream>>>(x);
    gscatter_k<<<C / 256, 256, 0, stream>>>(cg);
    finalize_k<<<G / 256, 256, 0, stream>>>(gamma, beta);
    cgather_k<<<C / 256, 256, 0, stream>>>(cg);
    norm_k<<<4096, 256, 0, stream>>>(x, out);
}

// Round 4
// 272.807 us; speedup vs baseline: 1.1513x; 1.1513x over previous
//
#include <hip/hip_runtime.h>

// GroupBatchNorm: B=512, C=65536, G=4096, fp32 in/out.
// Memory-bound: ~384 MiB min traffic -> ~61 us floor @ 6.3 TB/s.
//
// R4 pipeline (attacks R3's latency-bound colsum @ 1.1 TB/s, 33 MB atomic
// write churn):
//   zero_k   : zero the 3G group accumulators (48 KB)
//   colsum_k : per-channel partial sum/sumsq over 32 batch chunks.
//              8 float4 loads batched into registers for ILP (8 KB/wave in
//              flight), partials stored as plain float4 (NO atomics).
//   gsum_k   : reduce partials over chunks (coalesced), atomic scatter into
//              per-group accumulators (196K atomics over 12K addresses).
//   cfinal_k : per-channel fused scale/shift (group finalize recomputed
//              inline -- 16x redundant rsqrt, saves a kernel launch)
//   norm_k   : one float4 per thread: out = x*cscale[c] + cshift[c]

constexpr int B = 512;
constexpr int C = 65536;
constexpr int G = 4096;
constexpr int SPLIT = 32;         // batch chunks for stage-1 parallelism
constexpr int ROWS = B / SPLIT;   // 16 rows per chunk
constexpr int BATCH = 8;          // loads in flight per thread
#define EPS 1e-5f

// Device-global scratch (allocated at module load; no d_ws dependence).
__device__ float g_part1[SPLIT * C];   // 8 MB  per-chunk channel sums
__device__ float g_part2[SPLIT * C];   // 8 MB  per-chunk channel sumsq
__device__ float g_gsum[G];
__device__ float g_gsum2[G];
__device__ float g_gcnt[G];
__device__ float g_cscale[C];
__device__ float g_cshift[C];

__global__ __launch_bounds__(256) void zero_k() {
    int i = blockIdx.x * 256 + threadIdx.x;
    if (i < G) {
        g_gsum[i] = 0.0f;
        g_gsum2[i] = 0.0f;
        g_gcnt[i] = 0.0f;
    }
}

// Stage 1: thread owns 4 consecutive channels (one float4/row); 16 rows in
// two batches of 8 register-buffered loads. grid = (C/1024)*SPLIT = 2048.
__global__ __launch_bounds__(256) void colsum_k(const float* __restrict__ x) {
    const int nblk_c = C / 1024;                               // 64
    const int c4 = (blockIdx.x % nblk_c) * 256 + threadIdx.x;  // channel-quad
    const int chunk = blockIdx.x / nblk_c;
    const float4* __restrict__ xp =
        (const float4*)(x + (size_t)chunk * ROWS * C) + c4;
    float4 s = {0.f, 0.f, 0.f, 0.f};
    float4 s2 = {0.f, 0.f, 0.f, 0.f};
    float4 vbuf[BATCH];
    for (int base = 0; base < ROWS; base += BATCH) {
#pragma unroll
        for (int j = 0; j < BATCH; ++j)
            vbuf[j] = xp[(size_t)(base + j) * (C / 4)];
#pragma unroll
        for (int j = 0; j < BATCH; ++j) {
            float4 v = vbuf[j];
            s.x += v.x; s.y += v.y; s.z += v.z; s.w += v.w;
            s2.x = fmaf(v.x, v.x, s2.x);
            s2.y = fmaf(v.y, v.y, s2.y);
            s2.z = fmaf(v.z, v.z, s2.z);
            s2.w = fmaf(v.w, v.w, s2.w);
        }
    }
    ((float4*)g_part1)[(size_t)chunk * (C / 4) + c4] = s;
    ((float4*)g_part2)[(size_t)chunk * (C / 4) + c4] = s2;
}

// Stage 2: per-channel reduction over chunks, then group atomic scatter.
__global__ __launch_bounds__(256) void gsum_k(const int* __restrict__ cg) {
    const int c = blockIdx.x * 256 + threadIdx.x;
    float s = 0.f, s2 = 0.f;
#pragma unroll 8
    for (int k = 0; k < SPLIT; ++k) {
        s += g_part1[(size_t)k * C + c];
        s2 += g_part2[(size_t)k * C + c];
    }
    const int g = cg[c];
    atomicAdd(&g_gsum[g], s);
    atomicAdd(&g_gsum2[g], s2);
    atomicAdd(&g_gcnt[g], 1.0f);
}

// Stage 3: per-channel fused scale/shift (group math recomputed inline).
__global__ __launch_bounds__(256) void cfinal_k(const int* __restrict__ cg,
                                                const float* __restrict__ gamma,
                                                const float* __restrict__ beta) {
    const int c = blockIdx.x * 256 + threadIdx.x;
    const int g = cg[c];
    float cnt = fmaxf(g_gcnt[g] * (float)B, 1.0f);
    float mean = g_gsum[g] / cnt;
    float var = g_gsum2[g] / cnt - mean * mean;
    float inv = 1.0f / sqrtf(var + EPS);
    float sc = gamma[g] * inv;
    g_cscale[c] = sc;
    g_cshift[c] = fmaf(-mean, sc, beta[g]);
}

// Stage 4: streaming normalize, exactly one float4 per thread.
// grid = B*C/4/256 = 32768 blocks.
__global__ __launch_bounds__(256) void norm_k(const float* __restrict__ x,
                                              float* __restrict__ out) {
    const size_t i = (size_t)blockIdx.x * 256 + threadIdx.x;
    const int c4 = (int)(i & (C / 4 - 1));  // channel-quad (C/4 pow2)
    float4 xv = ((const float4*)x)[i];
    float4 s = ((const float4*)g_cscale)[c4];
    float4 t = ((const float4*)g_cshift)[c4];
    float4 o;
    o.x = fmaf(xv.x, s.x, t.x);
    o.y = fmaf(xv.y, s.y, t.y);
    o.z = fmaf(xv.z, s.z, t.z);
    o.w = fmaf(xv.w, s.w, t.w);
    ((float4*)out)[i] = o;
}

extern "C" void kernel_launch(void* const* d_in, const int* in_sizes, int n_in,
                              void* d_out, int out_size, void* d_ws, size_t ws_size,
                              hipStream_t stream) {
    const float* x = (const float*)d_in[0];
    const int* cg = (const int*)d_in[1];
    const float* gamma = (const float*)d_in[2];
    const float* beta = (const float*)d_in[3];
    float* out = (float*)d_out;
    (void)d_ws; (void)ws_size; (void)in_sizes; (void)n_in; (void)out_size;

    zero_k<<<(G + 255) / 256, 256, 0, stream>>>();
    colsum_k<<<(C / 1024) * SPLIT, 256, 0, stream>>>(x);
    gsum_k<<<C / 256, 256, 0, stream>>>(cg);
    cfinal_k<<<C / 256, 256, 0, stream>>>(cg, gamma, beta);
    norm_k<<<(B * C / 4) / 256, 256, 0, stream>>>(x, out);
}